// Round 2
// baseline (205.129 us; speedup 1.0000x reference)
//
#include <hip/hip_runtime.h>
#include <hip/hip_bf16.h>
#include <cstdint>

#define BATCH 8
#define NREP 12306          // N
#define OUTC 192            // TS^3*3
#define NBLOCKS 256
#define NTHREADS 256
#define RUNS_PER_BLOCK ((BATCH * OUTC) / NBLOCKS)   // 1536/256 = 6

__device__ __forceinline__ float gelu_exact(float x) {
    return 0.5f * x * (1.0f + erff(x * 0.70710678118654752f));
}
__device__ __forceinline__ float sigmoidf_(float x) {
    return 1.0f / (1.0f + __expf(-x));
}

// Device-scope grid barrier. ctr must be zeroed before launch (memsetAsync).
// All 256 blocks are co-resident (1 block/CU, 4 waves each), so spinning is safe.
__device__ __forceinline__ void grid_barrier(unsigned int* ctr) {
    __syncthreads();
    if (threadIdx.x == 0) {
        __threadfence();  // agent-scope release of this block's prior global writes
        __hip_atomic_fetch_add(ctr, 1u, __ATOMIC_RELEASE, __HIP_MEMORY_SCOPE_AGENT);
        while (__hip_atomic_load(ctr, __ATOMIC_ACQUIRE, __HIP_MEMORY_SCOPE_AGENT)
               < (unsigned int)NBLOCKS) {
            __builtin_amdgcn_s_sleep(1);
        }
        __threadfence();  // agent-scope acquire before reading other blocks' data
    }
    __syncthreads();
}

// One wave computes out[b][row] for all 8 batches. K in {256,512,1024}.
template <int K, int R, int ACT>  // ACT: 0 = gelu exact, 1 = sigmoid
__device__ __forceinline__ void gemv_body(const float* __restrict__ in,
                                          const float* __restrict__ W,
                                          const float* __restrict__ bias,
                                          float* __restrict__ out, int row) {
    const int lane = threadIdx.x & 63;
    constexpr int NV = K / 256;   // float4 loads per lane
    float4 wv[NV];
    const float4* Wrow = reinterpret_cast<const float4*>(W + (size_t)row * K);
#pragma unroll
    for (int i = 0; i < NV; ++i) wv[i] = Wrow[i * 64 + lane];

    float acc[BATCH];
#pragma unroll
    for (int b = 0; b < BATCH; ++b) {
        const float4* ib = reinterpret_cast<const float4*>(in + b * K);
        float a = 0.0f;
#pragma unroll
        for (int i = 0; i < NV; ++i) {
            const float4 iv = ib[i * 64 + lane];
            a = fmaf(wv[i].x, iv.x, a);
            a = fmaf(wv[i].y, iv.y, a);
            a = fmaf(wv[i].z, iv.z, a);
            a = fmaf(wv[i].w, iv.w, a);
        }
        acc[b] = a;
    }
#pragma unroll
    for (int b = 0; b < BATCH; ++b) {
#pragma unroll
        for (int s = 32; s > 0; s >>= 1) acc[b] += __shfl_xor(acc[b], s, 64);
    }
    if (lane == 0) {
        const float bb = bias[row];
#pragma unroll
        for (int b = 0; b < BATCH; ++b) {
            const float x = acc[b] + bb;
            out[b * R + row] = (ACT == 0) ? gelu_exact(x) : sigmoidf_(x);
        }
    }
}

__global__ __launch_bounds__(NTHREADS) void fused_decoder(
        const float* __restrict__ latent,
        const float* __restrict__ W1, const float* __restrict__ b1,
        const float* __restrict__ W2, const float* __restrict__ b2,
        const float* __restrict__ W3, const float* __restrict__ b3,
        const float* __restrict__ W4, const float* __restrict__ b4,
        float* __restrict__ h1, float* __restrict__ h2,
        float* __restrict__ h3, float* __restrict__ o,
        unsigned int* __restrict__ ctrs,
        float* __restrict__ out) {
    const int gw = blockIdx.x * (NTHREADS / 64) + (threadIdx.x >> 6);  // 0..1023

    // L1: 256 -> 512, gelu
    if (gw < 512)  gemv_body< 256,  512, 0>(latent, W1, b1, h1, gw);
    grid_barrier(ctrs + 0);
    // L2: 512 -> 1024, gelu
    if (gw < 1024) gemv_body< 512, 1024, 0>(h1, W2, b2, h2, gw);
    grid_barrier(ctrs + 1);
    // L3: 1024 -> 512, gelu
    if (gw < 512)  gemv_body<1024,  512, 0>(h2, W3, b3, h3, gw);
    grid_barrier(ctrs + 2);
    // L4: 512 -> 192, sigmoid
    if (gw < OUTC) gemv_body< 512, OUTC, 1>(h3, W4, b4, o, gw);
    grid_barrier(ctrs + 3);

    // Broadcast: 6 contiguous runs per block, each NREP copies of o[bp].
    const int t = threadIdx.x;
#pragma unroll
    for (int j = 0; j < RUNS_PER_BLOCK; ++j) {
        const int bp = blockIdx.x * RUNS_PER_BLOCK + j;
        const float v = o[bp];
        const size_t e0 = (size_t)bp * NREP;
        float* p = out + e0;
        const int mis  = (int)(e0 & 3);
        const int head = mis ? (4 - mis) : 0;
        if (t < head) p[t] = v;
        const int n4 = (NREP - head) >> 2;
        const float4 vv = make_float4(v, v, v, v);
        float4* p4 = reinterpret_cast<float4*>(p + head);
        for (int i = t; i < n4; i += NTHREADS) p4[i] = vv;
        const int done = head + (n4 << 2);
        if (t < NREP - done) p[done + t] = v;
    }
}

extern "C" void kernel_launch(void* const* d_in, const int* in_sizes, int n_in,
                              void* d_out, int out_size, void* d_ws, size_t ws_size,
                              hipStream_t stream) {
    const float* latent = (const float*)d_in[0];
    const float* W1 = (const float*)d_in[1];
    const float* b1 = (const float*)d_in[2];
    const float* W2 = (const float*)d_in[3];
    const float* b2 = (const float*)d_in[4];
    const float* W3 = (const float*)d_in[5];
    const float* b3 = (const float*)d_in[6];
    const float* W4 = (const float*)d_in[7];
    const float* b4 = (const float*)d_in[8];
    float* out = (float*)d_out;

    float* ws = (float*)d_ws;
    float* h1 = ws;                        // 8*512  = 4096 f
    float* h2 = h1 + BATCH * 512;          // 8*1024 = 8192 f
    float* h3 = h2 + BATCH * 1024;         // 8*512  = 4096 f
    float* o  = h3 + BATCH * 512;          // 8*192  = 1536 f
    unsigned int* ctrs = (unsigned int*)((char*)d_ws + 80 * 1024);  // past buffers

    hipMemsetAsync(ctrs, 0, 64, stream);
    fused_decoder<<<NBLOCKS, NTHREADS, 0, stream>>>(
        latent, W1, b1, W2, b2, W3, b3, W4, b4, h1, h2, h3, o, ctrs, out);
}

// Round 5
// 144.401 us; speedup vs baseline: 1.4206x; 1.4206x over previous
//
#include <hip/hip_runtime.h>
#include <hip/hip_bf16.h>
#include <cstdint>

#define BATCH 8
#define NREP 12306          // N
#define OUTC 192            // TS^3*3
#define NBLOCKS 256
#define NTHREADS 256
#define RUNS_PER_BLOCK ((BATCH * OUTC) / NBLOCKS)   // 6

__device__ __forceinline__ float gelu_exact(float x) {
    return 0.5f * x * (1.0f + erff(x * 0.70710678118654752f));
}
__device__ __forceinline__ float sigmoidf_(float x) {
    return 1.0f / (1.0f + __expf(-x));
}

// Grid barrier: RELAXED spin (no per-iteration cache invalidate),
// s_sleep backoff, ONE acquire fence at exit. Release fetch_add does the
// L2 writeback of this block's prior global writes.
__device__ __forceinline__ void grid_barrier(unsigned int* ctr) {
    __syncthreads();
    if (threadIdx.x == 0) {
        __hip_atomic_fetch_add(ctr, 1u, __ATOMIC_RELEASE, __HIP_MEMORY_SCOPE_AGENT);
        while (__hip_atomic_load(ctr, __ATOMIC_RELAXED, __HIP_MEMORY_SCOPE_AGENT)
               < (unsigned int)NBLOCKS) {
            __builtin_amdgcn_s_sleep(8);   // ~500 cycles between polls
        }
        __builtin_amdgcn_fence(__ATOMIC_ACQUIRE, "agent");  // one-time invalidate
    }
    __syncthreads();
}

// One wave computes out[b][row] for all 8 batches. K in {256,512,1024}.
template <int K, int R, int ACT>  // ACT: 0 = gelu exact, 1 = sigmoid
__device__ __forceinline__ void gemv_body(const float* __restrict__ in,
                                          const float* __restrict__ W,
                                          const float* __restrict__ bias,
                                          float* __restrict__ out, int row) {
    const int lane = threadIdx.x & 63;
    constexpr int NV = K / 256;   // float4 loads per lane
    float4 wv[NV];
    const float4* Wrow = reinterpret_cast<const float4*>(W + (size_t)row * K);
#pragma unroll
    for (int i = 0; i < NV; ++i) wv[i] = Wrow[i * 64 + lane];

    float acc[BATCH];
#pragma unroll
    for (int b = 0; b < BATCH; ++b) {
        const float4* ib = reinterpret_cast<const float4*>(in + b * K);
        float a = 0.0f;
#pragma unroll
        for (int i = 0; i < NV; ++i) {
            const float4 iv = ib[i * 64 + lane];
            a = fmaf(wv[i].x, iv.x, a);
            a = fmaf(wv[i].y, iv.y, a);
            a = fmaf(wv[i].z, iv.z, a);
            a = fmaf(wv[i].w, iv.w, a);
        }
        acc[b] = a;
    }
#pragma unroll
    for (int b = 0; b < BATCH; ++b) {
#pragma unroll
        for (int s = 32; s > 0; s >>= 1) acc[b] += __shfl_xor(acc[b], s, 64);
    }
    if (lane == 0) {
        const float bb = bias[row];
#pragma unroll
        for (int b = 0; b < BATCH; ++b) {
            const float x = acc[b] + bb;
            out[b * R + row] = (ACT == 0) ? gelu_exact(x) : sigmoidf_(x);
        }
    }
}

__global__ __launch_bounds__(NTHREADS) void fused_decoder(
        const float* __restrict__ latent,
        const float* __restrict__ W1, const float* __restrict__ b1,
        const float* __restrict__ W2, const float* __restrict__ b2,
        const float* __restrict__ W3, const float* __restrict__ b3,
        const float* __restrict__ W4, const float* __restrict__ b4,
        float* __restrict__ h1, float* __restrict__ h2,
        float* __restrict__ h3,
        unsigned int* __restrict__ ctrs,
        float* __restrict__ out) {
    const int wave = threadIdx.x >> 6;
    const int lane = threadIdx.x & 63;
    const int gw = blockIdx.x * (NTHREADS / 64) + wave;  // 0..1023

    // L1: 256 -> 512, gelu
    if (gw < 512)  gemv_body< 256,  512, 0>(latent, W1, b1, h1, gw);
    grid_barrier(ctrs + 0);
    // L2: 512 -> 1024, gelu
    gemv_body< 512, 1024, 0>(h1, W2, b2, h2, gw);
    grid_barrier(ctrs + 1);
    // L3: 1024 -> 512, gelu
    if (gw < 512)  gemv_body<1024,  512, 0>(h2, W3, b3, h3, gw);
    grid_barrier(ctrs + 2);

    // L4 (per-block, 6 sigmoid dots) + broadcast — no 4th barrier needed.
    __shared__ float s_o[RUNS_PER_BLOCK];
    for (int j = wave; j < RUNS_PER_BLOCK; j += NTHREADS / 64) {
        const int bp = blockIdx.x * RUNS_PER_BLOCK + j;
        const int b = bp / OUTC;
        const int p = bp - b * OUTC;
        const float4* hb = reinterpret_cast<const float4*>(h3 + b * 512);
        const float4* wr = reinterpret_cast<const float4*>(W4 + (size_t)p * 512);
        float a = 0.0f;
#pragma unroll
        for (int i = 0; i < 2; ++i) {
            const float4 x = hb[i * 64 + lane];
            const float4 w = wr[i * 64 + lane];
            a = fmaf(x.x, w.x, a); a = fmaf(x.y, w.y, a);
            a = fmaf(x.z, w.z, a); a = fmaf(x.w, w.w, a);
        }
#pragma unroll
        for (int s = 32; s > 0; s >>= 1) a += __shfl_xor(a, s, 64);
        if (lane == 0) s_o[j] = sigmoidf_(a + b4[p]);
    }
    __syncthreads();

    const int t = threadIdx.x;
#pragma unroll
    for (int j = 0; j < RUNS_PER_BLOCK; ++j) {
        const int bp = blockIdx.x * RUNS_PER_BLOCK + j;
        const float v = s_o[j];
        const size_t e0 = (size_t)bp * NREP;
        float* p = out + e0;
        const int mis  = (int)(e0 & 3);
        const int head = mis ? (4 - mis) : 0;
        if (t < head) p[t] = v;
        const int n4 = (NREP - head) >> 2;
        const float4 vv = make_float4(v, v, v, v);
        float4* p4 = reinterpret_cast<float4*>(p + head);
        for (int i = t; i < n4; i += NTHREADS) p4[i] = vv;
        const int done = head + (n4 << 2);
        if (t < NREP - done) p[done + t] = v;
    }
}

extern "C" void kernel_launch(void* const* d_in, const int* in_sizes, int n_in,
                              void* d_out, int out_size, void* d_ws, size_t ws_size,
                              hipStream_t stream) {
    const float* latent = (const float*)d_in[0];
    const float* W1 = (const float*)d_in[1];
    const float* b1 = (const float*)d_in[2];
    const float* W2 = (const float*)d_in[3];
    const float* b2 = (const float*)d_in[4];
    const float* W3 = (const float*)d_in[5];
    const float* b3 = (const float*)d_in[6];
    const float* W4 = (const float*)d_in[7];
    const float* b4 = (const float*)d_in[8];
    float* out = (float*)d_out;

    float* ws = (float*)d_ws;
    float* h1 = ws;                        // 8*512
    float* h2 = h1 + BATCH * 512;          // 8*1024
    float* h3 = h2 + BATCH * 1024;         // 8*512
    unsigned int* ctrs = (unsigned int*)((char*)d_ws + 80 * 1024);

    hipMemsetAsync(ctrs, 0, 64, stream);
    fused_decoder<<<NBLOCKS, NTHREADS, 0, stream>>>(
        latent, W1, b1, W2, b2, W3, b3, W4, b4, h1, h2, h3, ctrs, out);
}

// Round 6
// 114.722 us; speedup vs baseline: 1.7881x; 1.2587x over previous
//
#include <hip/hip_runtime.h>
#include <hip/hip_bf16.h>
#include <cstdint>

#define BATCH 8
#define NREP 12306          // N
#define OUTC 192            // TS^3*3

__device__ __forceinline__ float gelu_exact(float x) {
    return 0.5f * x * (1.0f + erff(x * 0.70710678118654752f));
}
__device__ __forceinline__ float sigmoidf_(float x) {
    return 1.0f / (1.0f + __expf(-x));
}

// Wave-per-row GEMV over 8 batches. block = 256 = 4 waves, 1 row/wave.
template <int K, int R, int ACT>
__global__ __launch_bounds__(256) void gemv_layer(const float* __restrict__ in,
                                                  const float* __restrict__ W,
                                                  const float* __restrict__ bias,
                                                  float* __restrict__ out) {
    const int wave = threadIdx.x >> 6;
    const int lane = threadIdx.x & 63;
    const int row  = blockIdx.x * 4 + wave;
    if (row >= R) return;

    constexpr int NV = K / 256;  // float4 loads per lane
    float4 wv[NV];
    const float4* Wrow = reinterpret_cast<const float4*>(W + (size_t)row * K);
#pragma unroll
    for (int i = 0; i < NV; ++i) wv[i] = Wrow[i * 64 + lane];

    float acc[BATCH];
#pragma unroll
    for (int b = 0; b < BATCH; ++b) {
        const float4* ib = reinterpret_cast<const float4*>(in + b * K);
        float a = 0.0f;
#pragma unroll
        for (int i = 0; i < NV; ++i) {
            const float4 iv = ib[i * 64 + lane];
            a = fmaf(wv[i].x, iv.x, a);
            a = fmaf(wv[i].y, iv.y, a);
            a = fmaf(wv[i].z, iv.z, a);
            a = fmaf(wv[i].w, iv.w, a);
        }
        acc[b] = a;
    }
#pragma unroll
    for (int b = 0; b < BATCH; ++b) {
#pragma unroll
        for (int s = 32; s > 0; s >>= 1) acc[b] += __shfl_xor(acc[b], s, 64);
    }
    if (lane == 0) {
        const float bb = bias[row];
#pragma unroll
        for (int b = 0; b < BATCH; ++b) {
            const float x = acc[b] + bb;
            out[b * R + row] = (ACT == 0) ? gelu_exact(x) : sigmoidf_(x);
        }
    }
}

// One block per (b,p) run: compute o[b][p] = sigmoid(W4[p]·h3[b] + b4[p])
// redundantly in every wave (butterfly reduce leaves the sum in all lanes),
// then stream NREP copies with aligned float4 stores. No LDS, no syncthreads.
__global__ __launch_bounds__(256) void l4_broadcast(const float* __restrict__ h3,
                                                    const float* __restrict__ W4,
                                                    const float* __restrict__ b4,
                                                    float* __restrict__ out) {
    const int bp = blockIdx.x;           // 0 .. 1535
    const int b  = bp / OUTC;
    const int p  = bp - b * OUTC;
    const int lane = threadIdx.x & 63;

    const float4* hb = reinterpret_cast<const float4*>(h3 + b * 512);
    const float4* wr = reinterpret_cast<const float4*>(W4 + (size_t)p * 512);
    float a = 0.0f;
#pragma unroll
    for (int i = 0; i < 2; ++i) {
        const float4 x = hb[i * 64 + lane];
        const float4 w = wr[i * 64 + lane];
        a = fmaf(x.x, w.x, a); a = fmaf(x.y, w.y, a);
        a = fmaf(x.z, w.z, a); a = fmaf(x.w, w.w, a);
    }
#pragma unroll
    for (int s = 32; s > 0; s >>= 1) a += __shfl_xor(a, s, 64);
    const float v = sigmoidf_(a + b4[p]);   // identical in all lanes

    const size_t e0 = (size_t)bp * NREP;
    float* ptr = out + e0;
    const int t = threadIdx.x;
    const int mis  = (int)(e0 & 3);
    const int head = mis ? (4 - mis) : 0;
    if (t < head) ptr[t] = v;
    const int n4 = (NREP - head) >> 2;
    const float4 vv = make_float4(v, v, v, v);
    float4* p4 = reinterpret_cast<float4*>(ptr + head);
    for (int i = t; i < n4; i += 256) p4[i] = vv;
    const int done = head + (n4 << 2);
    if (t < NREP - done) ptr[done + t] = v;
}

extern "C" void kernel_launch(void* const* d_in, const int* in_sizes, int n_in,
                              void* d_out, int out_size, void* d_ws, size_t ws_size,
                              hipStream_t stream) {
    const float* latent = (const float*)d_in[0];
    const float* W1 = (const float*)d_in[1];
    const float* b1 = (const float*)d_in[2];
    const float* W2 = (const float*)d_in[3];
    const float* b2 = (const float*)d_in[4];
    const float* W3 = (const float*)d_in[5];
    const float* b3 = (const float*)d_in[6];
    const float* W4 = (const float*)d_in[7];
    const float* b4 = (const float*)d_in[8];
    float* out = (float*)d_out;

    float* ws = (float*)d_ws;
    float* h1 = ws;                        // 8*512
    float* h2 = h1 + BATCH * 512;          // 8*1024
    float* h3 = h2 + BATCH * 1024;         // 8*512

    gemv_layer< 256,  512, 0><<<128, 256, 0, stream>>>(latent, W1, b1, h1);
    gemv_layer< 512, 1024, 0><<<256, 256, 0, stream>>>(h1,     W2, b2, h2);
    gemv_layer<1024,  512, 0><<<128, 256, 0, stream>>>(h2,     W3, b3, h3);
    l4_broadcast<<<BATCH * OUTC, 256, 0, stream>>>(h3, W4, b4, out);
}